// Round 1
// baseline (391.729 us; speedup 1.0000x reference)
//
#include <hip/hip_runtime.h>
#include <cstdint>
#include <cstddef>

#define NIMG 32
#define NCLS 81
#define NC1  80
#define NBOX 8732
#define CAP  65536
#define TOPK 400
#define MAXOUT 100
#define KW   7          // 400 bits -> 7 u64 words
#define COLCAP 4096
#define ROWCAP 2048

__device__ __forceinline__ unsigned int f2sort(float f) {
    unsigned int u = __float_as_uint(f);
    return (u & 0x80000000u) ? ~u : (u | 0x80000000u);
}

// ---------------- kernel 1: decode boxes + per-box softmax stats ----------------
__global__ void k_decode(const float* __restrict__ bboxes, const float* __restrict__ scores,
                         const float* __restrict__ dbox,
                         float4* __restrict__ oboxes, float2* __restrict__ oscale,
                         unsigned char* __restrict__ ovalid) {
    int gid = blockIdx.x * blockDim.x + threadIdx.x;
    if (gid >= NIMG * NBOX) return;
    int n = gid / NBOX, b = gid - n * NBOX;

    const float* bp = bboxes + (size_t)n * 4 * NBOX + b;
    float bx = bp[0], by = bp[NBOX], bw = bp[2 * NBOX], bh = bp[3 * NBOX];
    float4 d = reinterpret_cast<const float4*>(dbox)[b];   // (x,y,w,h) of default box

    float cx = 0.1f * bx * d.z + d.x;
    float cy = 0.1f * by * d.w + d.y;
    float ww = expf(0.2f * bw) * d.z;
    float hh = expf(0.2f * bh) * d.w;
    float l = cx - 0.5f * ww, t = cy - 0.5f * hh;
    float r = cx + 0.5f * ww, bo = cy + 0.5f * hh;
    l = fminf(fmaxf(l, 0.f), 1.f);  t  = fminf(fmaxf(t, 0.f), 1.f);
    r = fminf(fmaxf(r, 0.f), 1.f);  bo = fminf(fmaxf(bo, 0.f), 1.f);
    float w = r - l, h = bo - t;
    const float MINS = 1.0f / 300.0f;
    unsigned char v = (w >= MINS && h >= MINS) ? 1 : 0;

    const float* sp = scores + (size_t)n * NCLS * NBOX + b;
    float m = -3.4e38f;
    for (int c = 0; c < NCLS; ++c) m = fmaxf(m, sp[(size_t)c * NBOX]);
    float s = 0.f;
    for (int c = 0; c < NCLS; ++c) s += expf(sp[(size_t)c * NBOX] - m);

    oboxes[gid] = make_float4(l, t, r, bo);
    oscale[gid] = make_float2(m, s);
    ovalid[gid] = v;
}

// ---------------- kernel 2: candidate filter, one wave per (image,class) row ----------------
__global__ __launch_bounds__(64) void k_filter(const float* __restrict__ scores,
        const float2* __restrict__ scale, const unsigned char* __restrict__ valid,
        uint2* __restrict__ cand, int* __restrict__ cnt) {
    int row = blockIdx.x;                 // 0 .. NIMG*NC1-1
    int n = row / NC1, c1 = row - n * NC1, c = c1 + 1;
    int lane = threadIdx.x;
    __shared__ uint2 lbuf[ROWCAP];

    const float* sp = scores + ((size_t)n * NCLS + c) * NBOX;
    const float2* scp = scale + (size_t)n * NBOX;
    const unsigned char* vp = valid + (size_t)n * NBOX;

    int tot = 0;
    for (int b0 = 0; b0 < NBOX; b0 += 64) {
        int b = b0 + lane;
        bool v = false; float p = 0.f;
        if (b < NBOX) {
            float2 ms = scp[b];
            p = expf(sp[b] - ms.x) / ms.y;
            v = (p > 0.05f) && vp[b];
        }
        unsigned long long mask = __ballot(v);
        if (v) {
            int pos = tot + __popcll(mask & ((1ull << lane) - 1ull));
            if (pos < ROWCAP) lbuf[pos] = make_uint2(__float_as_uint(p), (unsigned)(b * NC1 + c1));
        }
        tot += (int)__popcll(mask);
    }
    if (tot > ROWCAP) tot = ROWCAP;
    int base = 0;
    if (lane == 0) base = atomicAdd(&cnt[n], tot);
    base = __shfl(base, 0);
    uint2* cp = cand + (size_t)n * CAP;
    for (int i = lane; i < tot; i += 64) {
        int pos = base + i;
        if (pos < CAP) cp[pos] = lbuf[i];
    }
}

// ---------------- bitonic sort (descending), u64 keys in LDS ----------------
__device__ void bitonic_desc(unsigned long long* arr, int n, int tid, int nt) {
    for (int k = 2; k <= n; k <<= 1) {
        for (int j = k >> 1; j > 0; j >>= 1) {
            __syncthreads();
            for (int i = tid; i < n; i += nt) {
                int ixj = i ^ j;
                if (ixj > i) {
                    unsigned long long a = arr[i], b = arr[ixj];
                    bool desc = ((i & k) == 0);
                    bool sw = desc ? (a < b) : (a > b);
                    if (sw) { arr[i] = b; arr[ixj] = a; }
                }
            }
        }
    }
    __syncthreads();
}

// ---------------- kernel 3: per-image top-400 + NMS + top-100 + output ----------------
__global__ __launch_bounds__(1024) void k_select(const float4* __restrict__ boxes,
        const uint2* __restrict__ cand, const int* __restrict__ cnt,
        float* __restrict__ out) {
    __shared__ int hist[1024];
    __shared__ unsigned long long keys[COLCAP];   // later reused as suppression rows
    __shared__ float  s_score[TOPK];
    __shared__ float4 s_cbox[TOPK];
    __shared__ int    s_label[TOPK];
    __shared__ float4 s_ob[TOPK];
    __shared__ float  s_area[TOPK];
    __shared__ unsigned long long s_keep[KW];
    __shared__ unsigned long long finkeys[512];
    __shared__ int s_T, s_pos;

    int n = blockIdx.x;
    int tid = threadIdx.x;
    int M = cnt[n]; if (M > CAP) M = CAP;
    const uint2* cp = cand + (size_t)n * CAP;

    for (int i = tid; i < 1024; i += 1024) hist[i] = 0;
    if (tid == 0) s_pos = 0;
    __syncthreads();

    // histogram on top bits of score
    for (int i = tid; i < M; i += 1024) {
        unsigned int bits = cp[i].x;
        int bk = (int)(bits >> 16) - 0x3D00;
        bk = max(0, min(1023, bk));
        atomicAdd(&hist[bk], 1);
    }
    __syncthreads();
    if (tid == 0) {
        int cum = 0, t = 1024;
        while (t > 0 && cum < TOPK) { --t; cum += hist[t]; }
        s_T = t;
    }
    __syncthreads();
    int T = s_T;

    // collect candidates in threshold-or-above buckets
    for (int i = tid; i < M; i += 1024) {
        uint2 e = cp[i];
        int bk = (int)(e.x >> 16) - 0x3D00;
        bk = max(0, min(1023, bk));
        if (bk >= T) {
            int p = atomicAdd(&s_pos, 1);
            if (p < COLCAP) keys[p] = ((unsigned long long)e.x << 32) | (unsigned int)(~e.y);
        }
    }
    __syncthreads();
    int ncol = min(s_pos, COLCAP);
    for (int i = ncol + tid; i < COLCAP; i += 1024) keys[i] = 0ull;
    __syncthreads();

    bitonic_desc(keys, COLCAP, tid, 1024);

    int nsel = min(TOPK, ncol);
    for (int i = tid; i < TOPK; i += 1024) {
        if (i < nsel) {
            unsigned long long key = keys[i];
            unsigned int bits = (unsigned int)(key >> 32);
            unsigned int flat = ~(unsigned int)key;
            int b = (int)(flat / NC1);
            int lab = (int)(flat - (unsigned)b * NC1) + 1;
            float sc = __uint_as_float(bits);
            float4 cb = boxes[(size_t)n * NBOX + b];
            s_score[i] = sc; s_cbox[i] = cb; s_label[i] = lab;
            float off = 2.0f * (float)lab;
            float4 ob = make_float4(cb.x + off, cb.y + off, cb.z + off, cb.w + off);
            s_ob[i] = ob;
            s_area[i] = fmaxf(ob.z - ob.x, 0.f) * fmaxf(ob.w - ob.y, 0.f);
        } else {
            s_score[i] = -1.0f;
            s_cbox[i] = make_float4(0.f, 0.f, 0.f, 0.f);
            s_label[i] = 0;
            s_ob[i] = make_float4(0.f, 0.f, 0.f, 0.f);
            s_area[i] = 0.f;
        }
    }
    __syncthreads();

    // build suppression bitmask rows (reuse `keys` LDS)
    unsigned long long* rows = keys;
    for (int t2 = tid; t2 < TOPK * KW; t2 += 1024) {
        int i = t2 / KW, w = t2 - (t2 / KW) * KW;
        unsigned long long bits = 0ull;
        if (i < nsel) {
            float4 oi = s_ob[i]; float ai = s_area[i];
            int j0 = w * 64;
            int jend = min(j0 + 64, nsel);
            for (int j = max(j0, i + 1); j < jend; ++j) {
                float4 oj = s_ob[j];
                float lx = fmaxf(oi.x, oj.x), ly = fmaxf(oi.y, oj.y);
                float rx = fminf(oi.z, oj.z), ry = fminf(oi.w, oj.w);
                float inter = fmaxf(rx - lx, 0.f) * fmaxf(ry - ly, 0.f);
                float uni = fmaxf(ai + s_area[j] - inter, 1e-12f);
                if (inter / uni > 0.5f) bits |= (1ull << (j - j0));
            }
        }
        rows[(size_t)i * KW + w] = bits;
    }
    if (tid == 0) {
        for (int w = 0; w < KW; ++w) {
            int lo = w * 64;
            unsigned long long kw;
            if (nsel >= lo + 64)      kw = ~0ull;
            else if (nsel <= lo)      kw = 0ull;
            else                      kw = (1ull << (nsel - lo)) - 1ull;
            s_keep[w] = kw;
        }
    }
    __syncthreads();

    // serial order-dependent suppression on wave 0 (lane w owns keep word w)
    if (tid < 64) {
        int lane = tid;
        unsigned long long keepw = (lane < KW) ? s_keep[lane] : 0ull;
        unsigned long long row = (lane < KW && nsel > 0) ? rows[lane] : 0ull;
        for (int i = 0; i < nsel; ++i) {
            unsigned long long nrow = (lane < KW && (i + 1) < nsel)
                                      ? rows[(size_t)(i + 1) * KW + lane] : 0ull;
            unsigned long long kwv = __shfl(keepw, i >> 6);
            if ((kwv >> (i & 63)) & 1ull) keepw &= ~row;
            row = nrow;
        }
        if (lane < KW) s_keep[lane] = keepw;
    }
    __syncthreads();

    // final stable top-100 over 400 slots
    for (int i = tid; i < 512; i += 1024) {
        unsigned long long key = 0ull;
        if (i < TOPK) {
            bool kb = (s_keep[i >> 6] >> (i & 63)) & 1ull;
            float fv = kb ? s_score[i] : -1.0f;
            key = ((unsigned long long)f2sort(fv) << 32) | (unsigned int)(~i);
        }
        finkeys[i] = key;
    }
    __syncthreads();
    bitonic_desc(finkeys, 512, tid, 1024);

    float* obox = out;
    float* olab = out + (size_t)NIMG * MAXOUT * 4;
    float* osco = out + (size_t)NIMG * MAXOUT * 5;
    for (int k = tid; k < MAXOUT; k += 1024) {
        unsigned long long key = finkeys[k];
        int slot = (int)(~(unsigned int)key);
        float4 cb = make_float4(0.f, 0.f, 0.f, 0.f);
        float lab = 0.f, sv = 0.f;
        if (slot >= 0 && slot < TOPK) {
            bool kb = (s_keep[slot >> 6] >> (slot & 63)) & 1ull;
            float fv = kb ? s_score[slot] : -1.0f;
            if (fv > 0.0f) {
                cb = s_cbox[slot];
                lab = (float)s_label[slot];
                sv = fv;
            }
        }
        size_t bo_ = ((size_t)n * MAXOUT + k) * 4;
        obox[bo_ + 0] = cb.x; obox[bo_ + 1] = cb.y; obox[bo_ + 2] = cb.z; obox[bo_ + 3] = cb.w;
        olab[(size_t)n * MAXOUT + k] = lab;
        osco[(size_t)n * MAXOUT + k] = sv;
    }
}

extern "C" void kernel_launch(void* const* d_in, const int* in_sizes, int n_in,
                              void* d_out, int out_size, void* d_ws, size_t ws_size,
                              hipStream_t stream) {
    (void)in_sizes; (void)n_in; (void)out_size; (void)ws_size;
    const float* bboxes = (const float*)d_in[0];
    const float* scores = (const float*)d_in[1];
    const float* dbox   = (const float*)d_in[2];
    float* out = (float*)d_out;

    char* ws = (char*)d_ws;
    size_t off = 0;
    float4* oboxes = (float4*)(ws + off); off += (size_t)NIMG * NBOX * sizeof(float4);
    float2* oscale = (float2*)(ws + off); off += (size_t)NIMG * NBOX * sizeof(float2);
    unsigned char* ovalid = (unsigned char*)(ws + off);
    off += (((size_t)NIMG * NBOX) + 255) & ~(size_t)255;
    int* cnt = (int*)(ws + off); off += 256;
    uint2* cand = (uint2*)(ws + off); off += (size_t)NIMG * CAP * sizeof(uint2);

    hipMemsetAsync(cnt, 0, NIMG * sizeof(int), stream);

    int tot = NIMG * NBOX;
    k_decode<<<(tot + 255) / 256, 256, 0, stream>>>(bboxes, scores, dbox, oboxes, oscale, ovalid);
    k_filter<<<NIMG * NC1, 64, 0, stream>>>(scores, oscale, ovalid, cand, cnt);
    k_select<<<NIMG, 1024, 0, stream>>>(oboxes, cand, cnt, out);
}

// Round 2
// 299.811 us; speedup vs baseline: 1.3066x; 1.3066x over previous
//
#include <hip/hip_runtime.h>
#include <cstdint>
#include <cstddef>

#define NIMG 32
#define NCLS 81
#define NC1  80
#define NBOX 8732
#define CAP  65536
#define TOPK 400
#define MAXOUT 100
#define KW   7          // 400 bits -> 7 u64 words
#define COLCAP 4096
#define WBUF 1280       // max candidates per wave: 64 boxes * 19 classes(p>0.05) = 1216

__device__ __forceinline__ unsigned int f2sort(float f) {
    unsigned int u = __float_as_uint(f);
    return (u & 0x80000000u) ? ~u : (u | 0x80000000u);
}

// ---------------- kernel 1: decode + softmax + candidate filter (fused) ----------------
__global__ __launch_bounds__(256) void k_decode(const float* __restrict__ bboxes,
        const float* __restrict__ scores, const float* __restrict__ dbox,
        float4* __restrict__ oboxes, uint2* __restrict__ cand, int* __restrict__ cnt) {
    int n = blockIdx.y;
    int b = blockIdx.x * 256 + threadIdx.x;
    int lane = threadIdx.x & 63;
    int wseg = (threadIdx.x >> 6) * WBUF;
    __shared__ uint2 lbuf[4 * WBUF];

    bool live = (b < NBOX);
    const float* sp = scores + (size_t)n * NCLS * NBOX + (live ? b : 0);

    bool go = false;
    float m = -3.4e38f, s = 0.f;
    if (live) {
        const float* bp = bboxes + (size_t)n * 4 * NBOX + b;
        float bx = bp[0], by = bp[NBOX], bw = bp[2 * NBOX], bh = bp[3 * NBOX];
        float4 d = reinterpret_cast<const float4*>(dbox)[b];
        float cx = 0.1f * bx * d.z + d.x;
        float cy = 0.1f * by * d.w + d.y;
        float ww = expf(0.2f * bw) * d.z;
        float hh = expf(0.2f * bh) * d.w;
        float l = cx - 0.5f * ww, t = cy - 0.5f * hh;
        float r = cx + 0.5f * ww, bo = cy + 0.5f * hh;
        l = fminf(fmaxf(l, 0.f), 1.f);  t  = fminf(fmaxf(t, 0.f), 1.f);
        r = fminf(fmaxf(r, 0.f), 1.f);  bo = fminf(fmaxf(bo, 0.f), 1.f);
        const float MINS = 1.0f / 300.0f;
        go = (r - l >= MINS) && (bo - t >= MINS);
        oboxes[(size_t)n * NBOX + b] = make_float4(l, t, r, bo);
    }

    if (go) {
        for (int c = 0; c < NCLS; ++c) m = fmaxf(m, sp[(size_t)c * NBOX]);
        for (int c = 0; c < NCLS; ++c) s += expf(sp[(size_t)c * NBOX] - m);
    }

    int wn = 0;
    for (int c = 1; c < NCLS; ++c) {
        bool v = false; float p = 0.f;
        if (go) {
            p = expf(sp[(size_t)c * NBOX] - m) / s;
            v = p > 0.05f;
        }
        unsigned long long mask = __ballot(v);
        if (v) {
            int pos = wn + __popcll(mask & ((1ull << lane) - 1ull));
            if (pos < WBUF) lbuf[wseg + pos] = make_uint2(__float_as_uint(p),
                                                          (unsigned)(b * NC1 + (c - 1)));
        }
        wn += (int)__popcll(mask);
    }
    if (wn > WBUF) wn = WBUF;
    int base = 0;
    if (lane == 0) base = atomicAdd(&cnt[n], wn);
    base = __shfl(base, 0);
    uint2* cp = cand + (size_t)n * CAP;
    for (int i = lane; i < wn; i += 64) {
        int pos = base + i;
        if (pos < CAP) cp[pos] = lbuf[wseg + i];
    }
}

// ---------------- bitonic sort (descending), u64 keys in LDS, n = pow2 ----------------
__device__ void bitonic_desc(unsigned long long* arr, int n, int tid, int nt) {
    for (int k = 2; k <= n; k <<= 1) {
        for (int j = k >> 1; j > 0; j >>= 1) {
            __syncthreads();
            for (int i = tid; i < n; i += nt) {
                int ixj = i ^ j;
                if (ixj > i) {
                    unsigned long long a = arr[i], b = arr[ixj];
                    bool desc = ((i & k) == 0);
                    bool sw = desc ? (a < b) : (a > b);
                    if (sw) { arr[i] = b; arr[ixj] = a; }
                }
            }
        }
    }
    __syncthreads();
}

// ---------------- kernel 2: per-image top-400 + NMS + top-100 + output ----------------
__global__ __launch_bounds__(1024) void k_select(const float4* __restrict__ boxes,
        const uint2* __restrict__ cand, const int* __restrict__ cnt,
        float* __restrict__ out) {
    __shared__ int hist[1024];
    __shared__ unsigned long long keys[COLCAP];   // later reused as suppression rows
    __shared__ float  s_score[TOPK];
    __shared__ float4 s_cbox[TOPK];
    __shared__ int    s_label[TOPK];
    __shared__ float4 s_ob[TOPK];
    __shared__ float  s_area[TOPK];
    __shared__ unsigned long long s_keep[KW];
    __shared__ unsigned long long finkeys[512];
    __shared__ int s_T, s_pos;

    int n = blockIdx.x;
    int tid = threadIdx.x;
    int M = cnt[n]; if (M > CAP) M = CAP;
    const uint2* cp = cand + (size_t)n * CAP;

    for (int i = tid; i < 1024; i += 1024) hist[i] = 0;
    if (tid == 0) s_pos = 0;
    __syncthreads();

    // histogram on top 16 bits of score (positive floats sort as unsigned)
    for (int i = tid; i < M; i += 1024) {
        unsigned int bits = cp[i].x;
        int bk = (int)(bits >> 16) - 0x3D00;
        bk = max(0, min(1023, bk));
        atomicAdd(&hist[bk], 1);
    }
    __syncthreads();
    if (tid == 0) {
        int cum = 0, t = 1024;
        while (t > 0 && cum < TOPK) { --t; cum += hist[t]; }
        s_T = t;
    }
    __syncthreads();
    int T = s_T;

    // collect candidates in threshold-or-above buckets
    for (int i = tid; i < M; i += 1024) {
        uint2 e = cp[i];
        int bk = (int)(e.x >> 16) - 0x3D00;
        bk = max(0, min(1023, bk));
        if (bk >= T) {
            int p = atomicAdd(&s_pos, 1);
            if (p < COLCAP) keys[p] = ((unsigned long long)e.x << 32) | (unsigned int)(~e.y);
        }
    }
    __syncthreads();
    int ncol = min(s_pos, COLCAP);

    // sort only the smallest pow2 >= ncol (usually 512, not 4096)
    int nsort = 512;
    while (nsort < ncol) nsort <<= 1;
    for (int i = ncol + tid; i < nsort; i += 1024) keys[i] = 0ull;
    __syncthreads();
    bitonic_desc(keys, nsort, tid, 1024);

    int nsel = min(TOPK, ncol);
    for (int i = tid; i < TOPK; i += 1024) {
        if (i < nsel) {
            unsigned long long key = keys[i];
            unsigned int bits = (unsigned int)(key >> 32);
            unsigned int flat = ~(unsigned int)key;
            int b = (int)(flat / NC1);
            int lab = (int)(flat - (unsigned)b * NC1) + 1;
            float sc = __uint_as_float(bits);
            float4 cb = boxes[(size_t)n * NBOX + b];
            s_score[i] = sc; s_cbox[i] = cb; s_label[i] = lab;
            float off = 2.0f * (float)lab;
            float4 ob = make_float4(cb.x + off, cb.y + off, cb.z + off, cb.w + off);
            s_ob[i] = ob;
            s_area[i] = fmaxf(ob.z - ob.x, 0.f) * fmaxf(ob.w - ob.y, 0.f);
        } else {
            s_score[i] = -1.0f;
            s_cbox[i] = make_float4(0.f, 0.f, 0.f, 0.f);
            s_label[i] = 0;
            s_ob[i] = make_float4(0.f, 0.f, 0.f, 0.f);
            s_area[i] = 0.f;
        }
    }
    __syncthreads();

    // build suppression rows: one thread per i, uniform j loop -> LDS broadcast reads
    unsigned long long* rows = keys;
    for (int i = tid; i < TOPK; i += 1024) {
        float4 oi = s_ob[i]; float ai = s_area[i];
        bool act = (i < nsel);
        #pragma unroll
        for (int w = 0; w < KW; ++w) {
            unsigned long long cur = 0ull;
            int j0 = w * 64;
            int jend = min(j0 + 64, nsel);
            if (act) {
                for (int j = j0; j < jend; ++j) {
                    float4 oj = s_ob[j];
                    float lx = fmaxf(oi.x, oj.x), ly = fmaxf(oi.y, oj.y);
                    float rx = fminf(oi.z, oj.z), ry = fminf(oi.w, oj.w);
                    float inter = fmaxf(rx - lx, 0.f) * fmaxf(ry - ly, 0.f);
                    float uni = fmaxf(ai + s_area[j] - inter, 1e-12f);
                    bool sup = (inter / uni > 0.5f) && (j > i);
                    cur |= ((unsigned long long)sup) << (j - j0);
                }
            }
            rows[(size_t)i * 8 + w] = cur;
        }
    }
    if (tid == 0) {
        for (int w = 0; w < KW; ++w) {
            int lo = w * 64;
            unsigned long long kw;
            if (nsel >= lo + 64)      kw = ~0ull;
            else if (nsel <= lo)      kw = 0ull;
            else                      kw = (1ull << (nsel - lo)) - 1ull;
            s_keep[w] = kw;
        }
    }
    __syncthreads();

    // serial order-dependent suppression on wave 0 (lane w owns keep word w)
    if (tid < 64) {
        int lane = tid;
        unsigned long long keepw = (lane < KW) ? s_keep[lane] : 0ull;
        unsigned long long row = (lane < KW && nsel > 0) ? rows[lane] : 0ull;
        for (int i = 0; i < nsel; ++i) {
            unsigned long long nrow = (lane < KW && (i + 1) < nsel)
                                      ? rows[(size_t)(i + 1) * 8 + lane] : 0ull;
            unsigned long long kwv = __shfl(keepw, i >> 6);
            if ((kwv >> (i & 63)) & 1ull) keepw &= ~row;
            row = nrow;
        }
        if (lane < KW) s_keep[lane] = keepw;
    }
    __syncthreads();

    // final stable top-100 over 400 slots
    for (int i = tid; i < 512; i += 1024) {
        unsigned long long key = 0ull;
        if (i < TOPK) {
            bool kb = (s_keep[i >> 6] >> (i & 63)) & 1ull;
            float fv = kb ? s_score[i] : -1.0f;
            key = ((unsigned long long)f2sort(fv) << 32) | (unsigned int)(~i);
        }
        finkeys[i] = key;
    }
    __syncthreads();
    bitonic_desc(finkeys, 512, tid, 1024);

    float* obox = out;
    float* olab = out + (size_t)NIMG * MAXOUT * 4;
    float* osco = out + (size_t)NIMG * MAXOUT * 5;
    for (int k = tid; k < MAXOUT; k += 1024) {
        unsigned long long key = finkeys[k];
        int slot = (int)(~(unsigned int)key);
        float4 cb = make_float4(0.f, 0.f, 0.f, 0.f);
        float lab = 0.f, sv = 0.f;
        if (slot >= 0 && slot < TOPK) {
            bool kb = (s_keep[slot >> 6] >> (slot & 63)) & 1ull;
            float fv = kb ? s_score[slot] : -1.0f;
            if (fv > 0.0f) {
                cb = s_cbox[slot];
                lab = (float)s_label[slot];
                sv = fv;
            }
        }
        size_t bo_ = ((size_t)n * MAXOUT + k) * 4;
        obox[bo_ + 0] = cb.x; obox[bo_ + 1] = cb.y; obox[bo_ + 2] = cb.z; obox[bo_ + 3] = cb.w;
        olab[(size_t)n * MAXOUT + k] = lab;
        osco[(size_t)n * MAXOUT + k] = sv;
    }
}

extern "C" void kernel_launch(void* const* d_in, const int* in_sizes, int n_in,
                              void* d_out, int out_size, void* d_ws, size_t ws_size,
                              hipStream_t stream) {
    (void)in_sizes; (void)n_in; (void)out_size; (void)ws_size;
    const float* bboxes = (const float*)d_in[0];
    const float* scores = (const float*)d_in[1];
    const float* dbox   = (const float*)d_in[2];
    float* out = (float*)d_out;

    char* ws = (char*)d_ws;
    size_t off = 0;
    float4* oboxes = (float4*)(ws + off); off += (size_t)NIMG * NBOX * sizeof(float4);
    int* cnt = (int*)(ws + off); off += 256;
    uint2* cand = (uint2*)(ws + off); off += (size_t)NIMG * CAP * sizeof(uint2);

    hipMemsetAsync(cnt, 0, NIMG * sizeof(int), stream);

    k_decode<<<dim3((NBOX + 255) / 256, NIMG), 256, 0, stream>>>(bboxes, scores, dbox,
                                                                 oboxes, cand, cnt);
    k_select<<<NIMG, 1024, 0, stream>>>(oboxes, cand, cnt, out);
}